// Round 1
// baseline (125.300 us; speedup 1.0000x reference)
//
#include <hip/hip_runtime.h>
#include <math.h>

#define B_SZ 32
#define N_SZ 512
#define IN_SZ 256
#define H_SZ 8
#define D_SZ 32
#define NEG_SLOPE 0.2f

// ---------------------------------------------------------------------------
// Kernel 1: Wx[m][n] = sum_k x[m][k] * W[n][k]
// M=16384, N=256, K=256. Tile 64x64, 256 threads, 4x4 micro-tile, f32.
// Output goes into d_out (same layout as final output; overwritten later).
// ---------------------------------------------------------------------------
__global__ __launch_bounds__(256) void gemm_xwt(const float* __restrict__ x,
                                                const float* __restrict__ W,
                                                float* __restrict__ Wx) {
    const int M = 16384, N = 256, K = 256;
    __shared__ __align__(16) float As[64][68];   // [m][k]   pad->68 (16B-mult stride)
    __shared__ __align__(16) float Bs[64][68];   // [k][n]   transposed store
    const int tid = threadIdx.x;
    const int m0 = blockIdx.x * 64;
    const int n0 = blockIdx.y * 64;
    const int ty = tid >> 4, tx = tid & 15;      // 16x16 threads
    float acc[4][4] = {};

    for (int kk = 0; kk < K; kk += 64) {
        // A tile: 64x64 floats = 1024 float4, 4 per thread (coalesced)
        #pragma unroll
        for (int c = 0; c < 4; ++c) {
            int idx = c * 256 + tid;          // 0..1023
            int row = idx >> 4;
            int k4  = idx & 15;
            float4 v = *(const float4*)(x + (size_t)(m0 + row) * K + kk + k4 * 4);
            *(float4*)&As[row][k4 * 4] = v;
        }
        // B tile transposed: Bs[k][n] = W[n0+n][kk+k]
        #pragma unroll
        for (int c = 0; c < 4; ++c) {
            int idx = c * 256 + tid;
            int row = idx >> 4;               // n-local
            int k4  = idx & 15;
            float4 v = *(const float4*)(W + (size_t)(n0 + row) * K + kk + k4 * 4);
            Bs[k4 * 4 + 0][row] = v.x;
            Bs[k4 * 4 + 1][row] = v.y;
            Bs[k4 * 4 + 2][row] = v.z;
            Bs[k4 * 4 + 3][row] = v.w;
        }
        __syncthreads();

        #pragma unroll
        for (int k4 = 0; k4 < 16; ++k4) {
            float a[4][4], bm[4][4];
            #pragma unroll
            for (int r = 0; r < 4; ++r) {
                float4 t = *(const float4*)&As[ty * 4 + r][k4 * 4];
                a[r][0] = t.x; a[r][1] = t.y; a[r][2] = t.z; a[r][3] = t.w;
            }
            #pragma unroll
            for (int q = 0; q < 4; ++q) {
                float4 t = *(const float4*)&Bs[k4 * 4 + q][tx * 4];
                bm[q][0] = t.x; bm[q][1] = t.y; bm[q][2] = t.z; bm[q][3] = t.w;
            }
            #pragma unroll
            for (int r = 0; r < 4; ++r)
                #pragma unroll
                for (int c = 0; c < 4; ++c)
                    #pragma unroll
                    for (int q = 0; q < 4; ++q)
                        acc[r][c] += a[r][q] * bm[q][c];
        }
        __syncthreads();
    }

    #pragma unroll
    for (int r = 0; r < 4; ++r) {
        float4 v;
        v.x = acc[r][0]; v.y = acc[r][1]; v.z = acc[r][2]; v.w = acc[r][3];
        *(float4*)(Wx + (size_t)(m0 + ty * 4 + r) * N + n0 + tx * 4) = v;
    }
}

// ---------------------------------------------------------------------------
// Kernel 2: s_src[b][h][n], s_tgt[b][h][n] = <Wx[b,n,h,:], a_src/tgt[h,:]>
// thread per (b,h,n), n fastest.
// ---------------------------------------------------------------------------
__global__ __launch_bounds__(256) void scores_k(const float* __restrict__ Wx,
                                                const float* __restrict__ attn,
                                                float* __restrict__ s_src,
                                                float* __restrict__ s_tgt) {
    int t = blockIdx.x * blockDim.x + threadIdx.x;   // 0 .. B*H*N-1
    int n  = t & (N_SZ - 1);
    int bh = t >> 9;
    int h  = bh & (H_SZ - 1);
    int b  = bh >> 3;
    const float* wx   = Wx + ((size_t)(b * N_SZ + n) * H_SZ + h) * D_SZ;
    const float* asrc = attn + h * (2 * D_SZ);
    const float* atgt = asrc + D_SZ;
    float ssum = 0.f, tsum = 0.f;
    #pragma unroll
    for (int d = 0; d < D_SZ; d += 4) {
        float4 w  = *(const float4*)(wx + d);
        float4 a1 = *(const float4*)(asrc + d);
        float4 a2 = *(const float4*)(atgt + d);
        ssum += w.x * a1.x + w.y * a1.y + w.z * a1.z + w.w * a1.w;
        tsum += w.x * a2.x + w.y * a2.y + w.z * a2.z + w.w * a2.w;
    }
    s_src[t] = ssum;
    s_tgt[t] = tsum;
}

// ---------------------------------------------------------------------------
// Kernel 3: fused softmax-attention + ELU. One block per (b,h), 512 threads,
// lane-per-row-i, single pass over j with online weighted accumulation.
// Reads Wx from d_out (staged fully into LDS before any write), writes d_out.
// ---------------------------------------------------------------------------
__global__ __launch_bounds__(512) void attn_k(const float* __restrict__ wx_g,
                                              const float* __restrict__ s_src,
                                              const float* __restrict__ s_tgt,
                                              float* __restrict__ out) {
    __shared__ __align__(16) float wx_s[N_SZ * D_SZ];   // 64 KB
    __shared__ float st_s[N_SZ];
    __shared__ float red[8];
    const int bh = blockIdx.x;
    const int h  = bh & (H_SZ - 1);
    const int b  = bh >> 3;
    const int tid = threadIdx.x;

    // stage Wx[b, :, h, :] -> LDS (coalesced 128B chunks)
    const float* wxg = wx_g + ((size_t)b * N_SZ * H_SZ + h) * D_SZ;
    #pragma unroll
    for (int c = 0; c < 8; ++c) {
        int idx = c * N_SZ + tid;       // 0..4095 float4 slots
        int j = idx >> 3, q = idx & 7;
        *(float4*)&wx_s[j * D_SZ + q * 4] =
            *(const float4*)(wxg + (size_t)j * H_SZ * D_SZ + q * 4);
    }

    // stage s_tgt row and compute block max
    float stv = s_tgt[bh * N_SZ + tid];
    st_s[tid] = stv;
    float m = stv;
    #pragma unroll
    for (int off = 32; off > 0; off >>= 1)
        m = fmaxf(m, __shfl_xor(m, off));
    if ((tid & 63) == 0) red[tid >> 6] = m;
    __syncthreads();
    float maxt = red[0];
    #pragma unroll
    for (int w = 1; w < 8; ++w) maxt = fmaxf(maxt, red[w]);

    // per-row single pass
    const int i = tid;
    const float ci = s_src[bh * N_SZ + i];
    float mi = ci + maxt;
    mi = fmaxf(mi, NEG_SLOPE * mi);          // lrelu (monotone -> max commutes)
    float acc[D_SZ];
    #pragma unroll
    for (int d = 0; d < D_SZ; ++d) acc[d] = 0.f;
    float denom = 0.f;

    #pragma unroll 2
    for (int j = 0; j < N_SZ; ++j) {
        float e = ci + st_s[j];
        e = fmaxf(e, NEG_SLOPE * e);
        float w = __expf(e - mi);
        denom += w;
        const float* wr = &wx_s[j * D_SZ];
        #pragma unroll
        for (int q = 0; q < 8; ++q) {
            float4 v = *(const float4*)(wr + q * 4);
            acc[q * 4 + 0] += w * v.x;
            acc[q * 4 + 1] += w * v.y;
            acc[q * 4 + 2] += w * v.z;
            acc[q * 4 + 3] += w * v.w;
        }
    }

    const float inv = 1.f / denom;
    float* og = out + ((size_t)(b * N_SZ + i) * H_SZ + h) * D_SZ;
    #pragma unroll
    for (int q = 0; q < 8; ++q) {
        float4 v;
        float o0 = acc[q * 4 + 0] * inv;
        float o1 = acc[q * 4 + 1] * inv;
        float o2 = acc[q * 4 + 2] * inv;
        float o3 = acc[q * 4 + 3] * inv;
        v.x = o0 > 0.f ? o0 : expm1f(o0);
        v.y = o1 > 0.f ? o1 : expm1f(o1);
        v.z = o2 > 0.f ? o2 : expm1f(o2);
        v.w = o3 > 0.f ? o3 : expm1f(o3);
        *(float4*)(og + q * 4) = v;
    }
}

// ---------------------------------------------------------------------------
extern "C" void kernel_launch(void* const* d_in, const int* in_sizes, int n_in,
                              void* d_out, int out_size, void* d_ws, size_t ws_size,
                              hipStream_t stream) {
    const float* x    = (const float*)d_in[0];   // (32,512,256)
    const float* W    = (const float*)d_in[1];   // (256,256)
    const float* attn = (const float*)d_in[2];   // (1,8,64)
    float* out = (float*)d_out;                  // (32,512,256)

    // d_out doubles as Wx scratch (identical [m][n] layout, n = h*32+d).
    float* Wx    = out;
    float* s_src = (float*)d_ws;                         // B*H*N floats
    float* s_tgt = s_src + B_SZ * H_SZ * N_SZ;           // B*H*N floats (1 MB total)

    dim3 g1(16384 / 64, 256 / 64);
    gemm_xwt<<<g1, 256, 0, stream>>>(x, W, Wx);

    scores_k<<<(B_SZ * H_SZ * N_SZ) / 256, 256, 0, stream>>>(Wx, attn, s_src, s_tgt);

    attn_k<<<B_SZ * H_SZ, 512, 0, stream>>>(Wx, s_src, s_tgt, out);
}

// Round 2
// 55.808 us; speedup vs baseline: 2.2452x; 2.2452x over previous
//
#include <hip/hip_runtime.h>
#include <math.h>

#define B_SZ 32
#define N_SZ 512
#define IN_SZ 256
#define H_SZ 8
#define D_SZ 32
#define NEG_SLOPE 0.2f
#define LOG2E 1.44269504088896f

typedef _Float16 f16x8 __attribute__((ext_vector_type(8)));
typedef float f32x4 __attribute__((ext_vector_type(4)));

union PK8 { uint4 u4; _Float16 h[8]; };
union PK4 { uint2 u2; _Float16 h[4]; };

// ---------------------------------------------------------------------------
// Kernel 1: Wx = x @ W.T via f16 MFMA (f32 accumulate).
// M=16384, K=256, N=256. Block tile 64(M) x 256(N), 256 thr = 4 waves,
// wave tile 32x128 (2 i-subtiles x 8 n-subtiles of 16x16). K chunked by 64.
// LDS tiles f16 with XOR swizzle byte ^= (row&7)<<4 on 16B granularity.
// ---------------------------------------------------------------------------
__global__ __launch_bounds__(256) void gemm_f16(const float* __restrict__ x,
                                                const float* __restrict__ W,
                                                float* __restrict__ Wx) {
    __shared__ unsigned short xs[64 * 64];    // [i][k] f16, row=128B
    __shared__ unsigned short ws[256 * 64];   // [n][k] f16, row=128B
    const int tid = threadIdx.x;
    const int m0 = blockIdx.x * 64;
    const int w = tid >> 6, l = tid & 63;
    const int iw = (w & 1) * 32;
    const int nw = (w >> 1) * 128;
    const int q = l >> 4, ln = l & 15;

    f32x4 acc[2][8];
    #pragma unroll
    for (int g = 0; g < 2; ++g)
        #pragma unroll
        for (int t = 0; t < 8; ++t) acc[g][t] = (f32x4){0.f, 0.f, 0.f, 0.f};

    for (int kc = 0; kc < 256; kc += 64) {
        __syncthreads();
        // stage x tile 64x64 f32 -> f16
        {
            const int i = tid >> 2, kq = tid & 3;
            const float* src = x + (size_t)(m0 + i) * 256 + kc + kq * 16;
            float4 v0 = *(const float4*)(src + 0);
            float4 v1 = *(const float4*)(src + 4);
            float4 v2 = *(const float4*)(src + 8);
            float4 v3 = *(const float4*)(src + 12);
            PK8 p0, p1;
            p0.h[0] = (_Float16)v0.x; p0.h[1] = (_Float16)v0.y;
            p0.h[2] = (_Float16)v0.z; p0.h[3] = (_Float16)v0.w;
            p0.h[4] = (_Float16)v1.x; p0.h[5] = (_Float16)v1.y;
            p0.h[6] = (_Float16)v1.z; p0.h[7] = (_Float16)v1.w;
            p1.h[0] = (_Float16)v2.x; p1.h[1] = (_Float16)v2.y;
            p1.h[2] = (_Float16)v2.z; p1.h[3] = (_Float16)v2.w;
            p1.h[4] = (_Float16)v3.x; p1.h[5] = (_Float16)v3.y;
            p1.h[6] = (_Float16)v3.z; p1.h[7] = (_Float16)v3.w;
            int b0 = i * 128 + kq * 32;
            *(uint4*)((char*)xs + (b0 ^ ((i & 7) << 4))) = p0.u4;
            *(uint4*)((char*)xs + ((b0 + 16) ^ ((i & 7) << 4))) = p1.u4;
        }
        // stage W tile 256x64 f32 -> f16 (16 passes of 16 rows)
        {
            const int kq = tid & 15, nr = tid >> 4;
            #pragma unroll
            for (int p = 0; p < 16; ++p) {
                int n = p * 16 + nr;
                float4 v = *(const float4*)(W + (size_t)n * 256 + kc + kq * 4);
                PK4 pk;
                pk.h[0] = (_Float16)v.x; pk.h[1] = (_Float16)v.y;
                pk.h[2] = (_Float16)v.z; pk.h[3] = (_Float16)v.w;
                int bb = n * 128 + kq * 8;
                *(uint2*)((char*)ws + (bb ^ ((n & 7) << 4))) = pk.u2;
            }
        }
        __syncthreads();

        #pragma unroll
        for (int ks = 0; ks < 2; ++ks) {
            const int kb = ks * 64 + q * 16;
            f16x8 af[2];
            #pragma unroll
            for (int g = 0; g < 2; ++g) {
                int row = iw + g * 16 + ln;
                uint4 raw = *(const uint4*)((const char*)xs +
                            ((row * 128 + kb) ^ ((row & 7) << 4)));
                PK8 pk; pk.u4 = raw;
                af[g] = *(f16x8*)&pk;
            }
            #pragma unroll
            for (int t = 0; t < 8; ++t) {
                int n = nw + t * 16 + ln;
                uint4 raw = *(const uint4*)((const char*)ws +
                            ((n * 128 + kb) ^ ((n & 7) << 4)));
                PK8 pk; pk.u4 = raw;
                f16x8 bf = *(f16x8*)&pk;
                acc[0][t] = __builtin_amdgcn_mfma_f32_16x16x32_f16(af[0], bf, acc[0][t], 0, 0, 0);
                acc[1][t] = __builtin_amdgcn_mfma_f32_16x16x32_f16(af[1], bf, acc[1][t], 0, 0, 0);
            }
        }
    }

    #pragma unroll
    for (int g = 0; g < 2; ++g)
        #pragma unroll
        for (int t = 0; t < 8; ++t)
            #pragma unroll
            for (int r = 0; r < 4; ++r) {
                int i = m0 + iw + g * 16 + q * 4 + r;
                int n = nw + t * 16 + ln;
                Wx[(size_t)i * 256 + n] = acc[g][t][r];
            }
}

// ---------------------------------------------------------------------------
// Kernel 2: s_src/s_tgt = <Wx[b,n,h,:], a_src/tgt[h,:]>  (f32, unchanged)
// ---------------------------------------------------------------------------
__global__ __launch_bounds__(256) void scores_k(const float* __restrict__ Wx,
                                                const float* __restrict__ attn,
                                                float* __restrict__ s_src,
                                                float* __restrict__ s_tgt) {
    int t = blockIdx.x * blockDim.x + threadIdx.x;
    int n  = t & (N_SZ - 1);
    int bh = t >> 9;
    int h  = bh & (H_SZ - 1);
    int b  = bh >> 3;
    const float* wx   = Wx + ((size_t)(b * N_SZ + n) * H_SZ + h) * D_SZ;
    const float* asrc = attn + h * (2 * D_SZ);
    const float* atgt = asrc + D_SZ;
    float ssum = 0.f, tsum = 0.f;
    #pragma unroll
    for (int d = 0; d < D_SZ; d += 4) {
        float4 wv = *(const float4*)(wx + d);
        float4 a1 = *(const float4*)(asrc + d);
        float4 a2 = *(const float4*)(atgt + d);
        ssum += wv.x * a1.x + wv.y * a1.y + wv.z * a1.z + wv.w * a1.w;
        tsum += wv.x * a2.x + wv.y * a2.y + wv.z * a2.z + wv.w * a2.w;
    }
    s_src[t] = ssum;
    s_tgt[t] = tsum;
}

// ---------------------------------------------------------------------------
// Kernel 3: fused softmax-attention + ELU via f16 MFMA.
// One block per (b,h): 512 thr = 8 waves, wave owns 64 rows (4 groups of 16).
// P fragments generated IN REGISTERS (no P LDS). WxT staged f16 [d][j] with
// XOR swizzle; st row staged f32. Stage-all-then-write => d_out reuse safe.
// ---------------------------------------------------------------------------
__global__ __launch_bounds__(512) void attn_k(const float* __restrict__ wx_g,
                                              const float* __restrict__ s_src,
                                              const float* __restrict__ s_tgt,
                                              float* __restrict__ out) {
    __shared__ unsigned short wxt[32 * 512];  // [d][j] f16, row=1024B, 32KB
    __shared__ float stf[N_SZ];               // s_tgt * LOG2E
    __shared__ float red_s[8];
    const int bh = blockIdx.x;
    const int h  = bh & (H_SZ - 1);
    const int b  = bh >> 3;
    const int tid = threadIdx.x;
    const int w = tid >> 6, l = tid & 63;
    const int q = l >> 4, ln = l & 15;

    // ---- stage WxT (f32 -> f16, transposed) ----
    {
        const int d = tid & 31, jseg = tid >> 5;   // 32 d x 16 jseg
        const float* base = wx_g + (size_t)(b * N_SZ + jseg * 32) * 256 + h * 32 + d;
        #pragma unroll
        for (int qq = 0; qq < 4; ++qq) {
            PK8 pk;
            #pragma unroll
            for (int s = 0; s < 8; ++s)
                pk.h[s] = (_Float16)base[(size_t)(qq * 8 + s) * 256];
            int bb = d * 1024 + (jseg * 32 + qq * 8) * 2;
            *(uint4*)((char*)wxt + (bb ^ ((d & 7) << 4))) = pk.u4;
        }
    }
    // ---- stage st (scaled by LOG2E) + block max of raw st ----
    float stv = s_tgt[bh * N_SZ + tid];
    stf[tid] = stv * LOG2E;
    {
        float m = stv;
        #pragma unroll
        for (int off = 32; off > 0; off >>= 1)
            m = fmaxf(m, __shfl_xor(m, off));
        if (l == 0) red_s[w] = m;
    }
    __syncthreads();
    float maxt = red_s[0];
    #pragma unroll
    for (int ww = 1; ww < 8; ++ww) maxt = fmaxf(maxt, red_s[ww]);

    // ---- per-lane row constants (4 groups of 16 rows per wave) ----
    float ciK[4], miK[4];
    #pragma unroll
    for (int g = 0; g < 4; ++g) {
        int i = w * 64 + g * 16 + ln;
        float ci = s_src[bh * N_SZ + i];
        float c = ci + maxt;
        float mi = fmaxf(c, NEG_SLOPE * c);
        ciK[g] = ci * LOG2E;
        miK[g] = mi * LOG2E;
    }

    f32x4 acc[4][2];
    #pragma unroll
    for (int g = 0; g < 4; ++g) {
        acc[g][0] = (f32x4){0.f, 0.f, 0.f, 0.f};
        acc[g][1] = (f32x4){0.f, 0.f, 0.f, 0.f};
    }
    float pd[4] = {0.f, 0.f, 0.f, 0.f};

    // ---- main loop: 16 K-steps of 32 j ----
    for (int kk = 0; kk < 16; ++kk) {
        const int j0 = kk * 32 + q * 8;
        float4 s0 = *(const float4*)(stf + j0);
        float4 s1 = *(const float4*)(stf + j0 + 4);
        float st[8] = {s0.x, s0.y, s0.z, s0.w, s1.x, s1.y, s1.z, s1.w};

        f16x8 bf[2];
        #pragma unroll
        for (int dt = 0; dt < 2; ++dt) {
            int d = dt * 16 + ln;
            int bb = d * 1024 + kk * 64 + q * 16;
            uint4 raw = *(const uint4*)((const char*)wxt + (bb ^ ((d & 7) << 4)));
            PK8 pk; pk.u4 = raw;
            bf[dt] = *(f16x8*)&pk;
        }

        #pragma unroll
        for (int g = 0; g < 4; ++g) {
            f16x8 pa;
            float s = 0.f;
            #pragma unroll
            for (int e = 0; e < 8; ++e) {
                float eK = ciK[g] + st[e];
                float lr = fmaxf(eK, NEG_SLOPE * eK);
                float p = exp2f(lr - miK[g]);
                s += p;
                pa[e] = (_Float16)p;
            }
            pd[g] += s;
            acc[g][0] = __builtin_amdgcn_mfma_f32_16x16x32_f16(pa, bf[0], acc[g][0], 0, 0, 0);
            acc[g][1] = __builtin_amdgcn_mfma_f32_16x16x32_f16(pa, bf[1], acc[g][1], 0, 0, 0);
        }
    }

    // ---- epilogue: denominators, ELU, store ----
    float inv[4];
    #pragma unroll
    for (int g = 0; g < 4; ++g) {
        float s = pd[g];
        s += __shfl_xor(s, 16);
        s += __shfl_xor(s, 32);
        inv[g] = 1.f / s;
    }
    #pragma unroll
    for (int g = 0; g < 4; ++g)
        #pragma unroll
        for (int dt = 0; dt < 2; ++dt)
            #pragma unroll
            for (int r = 0; r < 4; ++r) {
                int row = q * 4 + r;               // 0..15
                float dn = __shfl(inv[g], row);     // lane 'row' holds i=row
                float o = acc[g][dt][r] * dn;
                o = o > 0.f ? o : (__expf(o) - 1.f);
                size_t i = (size_t)(b * N_SZ + w * 64 + g * 16 + row);
                out[i * 256 + h * 32 + dt * 16 + ln] = o;
            }
}

// ---------------------------------------------------------------------------
extern "C" void kernel_launch(void* const* d_in, const int* in_sizes, int n_in,
                              void* d_out, int out_size, void* d_ws, size_t ws_size,
                              hipStream_t stream) {
    const float* x    = (const float*)d_in[0];   // (32,512,256)
    const float* W    = (const float*)d_in[1];   // (256,256)
    const float* attn = (const float*)d_in[2];   // (1,8,64)
    float* out = (float*)d_out;                  // (32,512,256)

    float* Wx    = out;                                  // d_out doubles as Wx
    float* s_src = (float*)d_ws;                         // B*H*N f32
    float* s_tgt = s_src + B_SZ * H_SZ * N_SZ;           // B*H*N f32

    gemm_f16<<<16384 / 64, 256, 0, stream>>>(x, W, Wx);
    scores_k<<<(B_SZ * H_SZ * N_SZ) / 256, 256, 0, stream>>>(Wx, attn, s_src, s_tgt);
    attn_k<<<B_SZ * H_SZ, 512, 0, stream>>>(Wx, s_src, s_tgt, out);
}

// Round 5
// 42.868 us; speedup vs baseline: 2.9229x; 1.3019x over previous
//
#include <hip/hip_runtime.h>
#include <math.h>

#define NEG_SLOPE 0.2f
#define LOG2E 1.44269504088896f

typedef _Float16 f16x8 __attribute__((ext_vector_type(8)));
typedef float f32x4 __attribute__((ext_vector_type(4)));

union PK8 { uint4 u4; _Float16 h[8]; };
union PK4 { uint2 u2; _Float16 h[4]; };
union PK1 { unsigned short u; _Float16 h; };

// ---------------------------------------------------------------------------
// Fully fused GAT layer. One block per (b,h): 512 threads = 8 waves.
// Phase 1: slice-GEMM  WxT[d][j] = sum_k W[h*32+d][k] * x[b][j][k]
//          (f16 MFMA, A = W-slice (m=d), B = x rows (n=j), K chunked by 64)
// Phase 2: epilogue — scores s_src/s_tgt from f32 accumulators (in-register
//          dot with attn vec + shfl reduce), WxT -> f16 LDS (swizzled).
// Phase 3: softmax + PV via f16 MFMA with in-register P generation + ELU.
// Wx and scores NEVER touch global memory. Block mapping b = bid&31 puts all
// 8 heads of a batch on one XCD (blockIdx round-robins XCDs mod 8) so x[b]
// is HBM-fetched once and L2-served for the other 7 heads.
// ---------------------------------------------------------------------------
__global__ __launch_bounds__(512) void gat_fused(const float* __restrict__ x,
                                                 const float* __restrict__ W,
                                                 const float* __restrict__ attn,
                                                 float* __restrict__ out) {
    __shared__ __align__(16) unsigned short Ws[32 * 256];   // [d][k] f16, row 512B, swz (d&7)<<4
    __shared__ __align__(16) unsigned short Xs[512 * 64];   // [j][k] f16, row 128B, swz (j&7)<<4
    __shared__ __align__(16) unsigned short wxt[32 * 512];  // [d][j] f16, row 1024B, swz (d&7)<<4
    __shared__ float stf[512];    // s_tgt * LOG2E
    __shared__ float ssrc[512];   // s_src * LOG2E
    __shared__ float red_s[8];

    const int bid = blockIdx.x;
    const int b = bid & 31, h = bid >> 5;       // same-b blocks share an XCD
    const int tid = threadIdx.x;
    const int w = tid >> 6, l = tid & 63;
    const int q = l >> 4, ln = l & 15;

    // ---- per-lane attn vector slices (hoisted; tiny, L2/L3-resident) ----
    float av_s[2][4], av_t[2][4];
    #pragma unroll
    for (int dt = 0; dt < 2; ++dt)
        #pragma unroll
        for (int r = 0; r < 4; ++r) {
            int d = dt * 16 + q * 4 + r;
            av_s[dt][r] = attn[h * 64 + d];
            av_t[dt][r] = attn[h * 64 + 32 + d];
        }

    // ---- stage W slice: 32 rows x 256 k, f32 -> f16 ----
    #pragma unroll
    for (int p = 0; p < 4; ++p) {
        int idx = p * 512 + tid;            // 2048 float4 slots
        int d = idx >> 6, kq = idx & 63;
        float4 v = *(const float4*)(W + (size_t)(h * 32 + d) * 256 + kq * 4);
        PK4 pk;
        pk.h[0] = (_Float16)v.x; pk.h[1] = (_Float16)v.y;
        pk.h[2] = (_Float16)v.z; pk.h[3] = (_Float16)v.w;
        *(uint2*)((char*)Ws + ((d * 512 + kq * 8) ^ ((d & 7) << 4))) = pk.u2;
    }

    // ---- Phase 1: slice GEMM, K chunked by 64 ----
    f32x4 gacc[2][4];
    #pragma unroll
    for (int dt = 0; dt < 2; ++dt)
        #pragma unroll
        for (int jt = 0; jt < 4; ++jt) gacc[dt][jt] = (f32x4){0.f, 0.f, 0.f, 0.f};

    const float* xb = x + (size_t)b * 512 * 256;
    for (int c4 = 0; c4 < 4; ++c4) {
        __syncthreads();   // Xs reusable (also orders Ws writes before first read)
        // stage x chunk: 512 rows x 64 k f32 -> f16
        #pragma unroll
        for (int pp = 0; pp < 4; ++pp) {
            int j = pp * 128 + (tid >> 2);
            int kseg = (tid & 3) * 16;
            const float* src = xb + (size_t)j * 256 + c4 * 64 + kseg;
            float4 v0 = *(const float4*)(src + 0);
            float4 v1 = *(const float4*)(src + 4);
            float4 v2 = *(const float4*)(src + 8);
            float4 v3 = *(const float4*)(src + 12);
            PK8 p0, p1;
            p0.h[0] = (_Float16)v0.x; p0.h[1] = (_Float16)v0.y;
            p0.h[2] = (_Float16)v0.z; p0.h[3] = (_Float16)v0.w;
            p0.h[4] = (_Float16)v1.x; p0.h[5] = (_Float16)v1.y;
            p0.h[6] = (_Float16)v1.z; p0.h[7] = (_Float16)v1.w;
            p1.h[0] = (_Float16)v2.x; p1.h[1] = (_Float16)v2.y;
            p1.h[2] = (_Float16)v2.z; p1.h[3] = (_Float16)v2.w;
            p1.h[4] = (_Float16)v3.x; p1.h[5] = (_Float16)v3.y;
            p1.h[6] = (_Float16)v3.z; p1.h[7] = (_Float16)v3.w;
            int base = j * 128 + kseg * 2;
            *(uint4*)((char*)Xs + ((base) ^ ((j & 7) << 4))) = p0.u4;
            *(uint4*)((char*)Xs + ((base + 16) ^ ((j & 7) << 4))) = p1.u4;
        }
        __syncthreads();
        // compute: 2 K-steps of 32
        #pragma unroll
        for (int ks = 0; ks < 2; ++ks) {
            f16x8 af[2];
            #pragma unroll
            for (int dt = 0; dt < 2; ++dt) {
                int d = dt * 16 + ln;
                int bb = d * 512 + c4 * 128 + ks * 64 + q * 16;
                uint4 raw = *(const uint4*)((const char*)Ws + (bb ^ ((d & 7) << 4)));
                PK8 pk; pk.u4 = raw;
                af[dt] = *(f16x8*)&pk;
            }
            #pragma unroll
            for (int jt = 0; jt < 4; ++jt) {
                int j = w * 64 + jt * 16 + ln;
                int bb = j * 128 + ks * 64 + q * 16;
                uint4 raw = *(const uint4*)((const char*)Xs + (bb ^ ((j & 7) << 4)));
                PK8 pk; pk.u4 = raw;
                f16x8 bf = *(f16x8*)&pk;
                gacc[0][jt] = __builtin_amdgcn_mfma_f32_16x16x32_f16(af[0], bf, gacc[0][jt], 0, 0, 0);
                gacc[1][jt] = __builtin_amdgcn_mfma_f32_16x16x32_f16(af[1], bf, gacc[1][jt], 0, 0, 0);
            }
        }
    }

    // ---- Phase 2: epilogue — scores in-register + WxT -> LDS ----
    // C layout: row(=d within tile) = q*4+r, col(=j) = ln.
    #pragma unroll
    for (int jt = 0; jt < 4; ++jt) {
        float ps = 0.f, pt = 0.f;
        #pragma unroll
        for (int dt = 0; dt < 2; ++dt)
            #pragma unroll
            for (int r = 0; r < 4; ++r) {
                float v = gacc[dt][jt][r];
                ps += v * av_s[dt][r];
                pt += v * av_t[dt][r];
            }
        ps += __shfl_xor(ps, 16); ps += __shfl_xor(ps, 32);
        pt += __shfl_xor(pt, 16); pt += __shfl_xor(pt, 32);
        int j = w * 64 + jt * 16 + ln;
        if (q == 0) { ssrc[j] = ps * LOG2E; stf[j] = pt * LOG2E; }
        #pragma unroll
        for (int dt = 0; dt < 2; ++dt)
            #pragma unroll
            for (int r = 0; r < 4; ++r) {
                int d = dt * 16 + q * 4 + r;
                PK1 hv; hv.h = (_Float16)gacc[dt][jt][r];
                *(unsigned short*)((char*)wxt + (((d << 10) + j * 2) ^ ((d & 7) << 4))) = hv.u;
            }
    }
    __syncthreads();

    // ---- Phase 3: softmax + PV + ELU (proven structure) ----
    // block max of scaled s_tgt (max commutes with positive scaling)
    {
        float m = stf[tid];
        #pragma unroll
        for (int off = 32; off > 0; off >>= 1)
            m = fmaxf(m, __shfl_xor(m, off));
        if (l == 0) red_s[w] = m;
    }
    __syncthreads();
    float maxtK = red_s[0];
    #pragma unroll
    for (int ww = 1; ww < 8; ++ww) maxtK = fmaxf(maxtK, red_s[ww]);

    float ciK[4], miK[4];
    #pragma unroll
    for (int g = 0; g < 4; ++g) {
        int i = w * 64 + g * 16 + ln;
        float cc = ssrc[i];                       // scaled
        float c = cc + maxtK;
        miK[g] = fmaxf(c, NEG_SLOPE * c);         // lrelu in log2-scaled domain
        ciK[g] = cc;
    }

    f32x4 acc[4][2];
    #pragma unroll
    for (int g = 0; g < 4; ++g) {
        acc[g][0] = (f32x4){0.f, 0.f, 0.f, 0.f};
        acc[g][1] = (f32x4){0.f, 0.f, 0.f, 0.f};
    }
    float pd[4] = {0.f, 0.f, 0.f, 0.f};

    for (int kk = 0; kk < 16; ++kk) {
        const int j0 = kk * 32 + q * 8;
        float4 s0 = *(const float4*)(stf + j0);
        float4 s1 = *(const float4*)(stf + j0 + 4);
        float st[8] = {s0.x, s0.y, s0.z, s0.w, s1.x, s1.y, s1.z, s1.w};

        f16x8 bf[2];
        #pragma unroll
        for (int dt = 0; dt < 2; ++dt) {
            int d = dt * 16 + ln;
            int bb = d * 1024 + kk * 64 + q * 16;
            uint4 raw = *(const uint4*)((const char*)wxt + (bb ^ ((d & 7) << 4)));
            PK8 pk; pk.u4 = raw;
            bf[dt] = *(f16x8*)&pk;
        }

        #pragma unroll
        for (int g = 0; g < 4; ++g) {
            f16x8 pa;
            float s = 0.f;
            #pragma unroll
            for (int e = 0; e < 8; ++e) {
                float eK = ciK[g] + st[e];
                float lr = fmaxf(eK, NEG_SLOPE * eK);
                float p = exp2f(lr - miK[g]);
                s += p;
                pa[e] = (_Float16)p;
            }
            pd[g] += s;
            acc[g][0] = __builtin_amdgcn_mfma_f32_16x16x32_f16(pa, bf[0], acc[g][0], 0, 0, 0);
            acc[g][1] = __builtin_amdgcn_mfma_f32_16x16x32_f16(pa, bf[1], acc[g][1], 0, 0, 0);
        }
    }

    float inv[4];
    #pragma unroll
    for (int g = 0; g < 4; ++g) {
        float s = pd[g];
        s += __shfl_xor(s, 16);
        s += __shfl_xor(s, 32);
        inv[g] = 1.f / s;
    }
    #pragma unroll
    for (int g = 0; g < 4; ++g)
        #pragma unroll
        for (int dt = 0; dt < 2; ++dt)
            #pragma unroll
            for (int r = 0; r < 4; ++r) {
                int row = q * 4 + r;
                float dn = __shfl(inv[g], row);    // lane 'row' (q=0) holds row's denom
                float o = acc[g][dt][r] * dn;
                o = o > 0.f ? o : (__expf(o) - 1.f);
                size_t i = (size_t)(b * 512 + w * 64 + g * 16 + row);
                out[i * 256 + h * 32 + dt * 16 + ln] = o;
            }
}

// ---------------------------------------------------------------------------
extern "C" void kernel_launch(void* const* d_in, const int* in_sizes, int n_in,
                              void* d_out, int out_size, void* d_ws, size_t ws_size,
                              hipStream_t stream) {
    const float* x    = (const float*)d_in[0];   // (32,512,256)
    const float* W    = (const float*)d_in[1];   // (256,256)
    const float* attn = (const float*)d_in[2];   // (1,8,64)
    float* out = (float*)d_out;                  // (32,512,256)

    gat_fused<<<256, 512, 0, stream>>>(x, W, attn, out);
}